// Round 9
// baseline (90.668 us; speedup 1.0000x reference)
//
#include <hip/hip_runtime.h>
#include <hip/hip_cooperative_groups.h>
#include <hip/hip_bf16.h>

namespace cg = cooperative_groups;

#define CAP 8
#define EPSF 1e-8f
#define NMS_THR 0.7f
#define TOPN 1000
#define ITILE 16                      // i-rows per tile
#define QCAP (256 * ITILE)            // worst-case survivors per tile
#define CAPR 240                      // nonzero rows cached in LDS (240*256B=60KB)
#define NBLOCKS 256                   // cooperative grid: 1 block/CU guaranteed

#define GLOBAL_AS __attribute__((address_space(1)))
#define LDS_AS    __attribute__((address_space(3)))

// ---------------------------------------------------------------------------
// Rotated-rect intersection area from center/size/cos/sin. Faithful fp32 port
// of the reference Sutherland-Hodgman clip (crossing-before-current emission,
// denom clamped to +EPS, CAP=8 truncation, shoelace with abs). ALL indices
// compile-time -> zero scratch, fully branchless. Verified absmax==0 R1-R8.
// ---------------------------------------------------------------------------
__device__ __forceinline__ float rect_inter_area_cs(
    float xc1, float yc1, float w1, float h1, float c1, float s1,
    float xc2, float yc2, float w2, float h2, float c2, float s2)
{
    float px[CAP], py[CAP];
    {
        float lx0 = -0.5f * w1, lx1 = 0.5f * w1;
        float ly0 = -0.5f * h1, ly1 = 0.5f * h1;
        px[0] = xc1 + lx0 * c1 - ly0 * s1;  py[0] = yc1 + lx0 * s1 + ly0 * c1;
        px[1] = xc1 + lx1 * c1 - ly0 * s1;  py[1] = yc1 + lx1 * s1 + ly0 * c1;
        px[2] = xc1 + lx1 * c1 - ly1 * s1;  py[2] = yc1 + lx1 * s1 + ly1 * c1;
        px[3] = xc1 + lx0 * c1 - ly1 * s1;  py[3] = yc1 + lx0 * s1 + ly1 * c1;
#pragma unroll
        for (int s2i = 4; s2i < CAP; ++s2i) { px[s2i] = 0.f; py[s2i] = 0.f; }
    }
    float qx[4], qy[4];
    {
        float lx0 = -0.5f * w2, lx1 = 0.5f * w2;
        float ly0 = -0.5f * h2, ly1 = 0.5f * h2;
        qx[0] = xc2 + lx0 * c2 - ly0 * s2;  qy[0] = yc2 + lx0 * s2 + ly0 * c2;
        qx[1] = xc2 + lx1 * c2 - ly0 * s2;  qy[1] = yc2 + lx1 * s2 + ly0 * c2;
        qx[2] = xc2 + lx1 * c2 - ly1 * s2;  qy[2] = yc2 + lx1 * s2 + ly1 * c2;
        qx[3] = xc2 + lx0 * c2 - ly1 * s2;  qy[3] = yc2 + lx0 * s2 + ly1 * c2;
    }

    int n = 4;
#pragma unroll
    for (int e = 0; e < 4; ++e) {
        float p0x = qx[e], p0y = qy[e];
        float ex = qx[(e + 1) & 3] - p0x, ey = qy[(e + 1) & 3] - p0y;

        float pxp = px[0], pyp = py[0];
#pragma unroll
        for (int s = 1; s < CAP; ++s)
            if (s == n - 1) { pxp = px[s]; pyp = py[s]; }
        float dp = ex * (pyp - p0y) - ey * (pxp - p0x);

        float nx_[CAP], ny_[CAP];
#pragma unroll
        for (int s = 0; s < CAP; ++s) { nx_[s] = 0.f; ny_[s] = 0.f; }
        int m = 0;

#pragma unroll
        for (int k = 0; k < CAP; ++k) {
            bool act = (k < n);
            float pxc = px[k], pyc = py[k];
            float dc = ex * (pyc - p0y) - ey * (pxc - p0x);
            bool cin = (dc >= 0.0f), pin = (dp >= 0.0f);

            float den = dp - dc;
            den = (fabsf(den) < EPSF) ? EPSF : den;
            float t = dp / den;
            float ix = pxp + t * (pxc - pxp);
            float iy = pyp + t * (pyc - pyp);

            bool emit_cross = act && (cin != pin);
            if (emit_cross) {
#pragma unroll
                for (int s = 0; s < CAP; ++s)
                    if (s == m) { nx_[s] = ix; ny_[s] = iy; }
                ++m;
            }
            bool emit_cur = act && cin;
            if (emit_cur) {
#pragma unroll
                for (int s = 0; s < CAP; ++s)
                    if (s == m) { nx_[s] = pxc; ny_[s] = pyc; }
                ++m;
            }
            if (act) { pxp = pxc; pyp = pyc; dp = dc; }
        }
        n = (m < CAP) ? m : CAP;
#pragma unroll
        for (int s = 0; s < CAP; ++s) { px[s] = nx_[s]; py[s] = ny_[s]; }
    }

    if (n < 3) return 0.0f;
    float s = 0.0f;
#pragma unroll
    for (int k = 0; k < CAP; ++k) {
        if (k < n) {
            float nxk = px[(k + 1) & (CAP - 1)];
            float nyk = py[(k + 1) & (CAP - 1)];
            if (k == n - 1) { nxk = px[0]; nyk = py[0]; }
            s += px[k] * nyk - py[k] * nxk;
        }
    }
    return 0.5f * fabsf(s);
}

__device__ __forceinline__ unsigned long long rl64(unsigned long long v, int l) {
    unsigned int lo = (unsigned int)__builtin_amdgcn_readlane((int)(unsigned int)v, l);
    unsigned int hi = (unsigned int)__builtin_amdgcn_readlane((int)(v >> 32), l);
    return ((unsigned long long)hi << 32) | lo;
}

// ---------------------------------------------------------------------------
// Single cooperative kernel: phase 0 init -> grid.sync -> phase 1 tiled
// filter (persistent over live tiles) -> grid.sync -> phase 2 greedy (block 0
// only). LDS is a phase-overlaid union: filter q[QCAP] (16KB) vs greedy
// rowdat (60KB) + rowlist. All phase bodies are the verified R8 algorithms.
// ---------------------------------------------------------------------------
__global__ __launch_bounds__(256, 1)
void fused_kernel(const float* __restrict__ boxes, float4* __restrict__ box8,
                  unsigned long long* __restrict__ mask,
                  unsigned long long* __restrict__ summary,
                  int* __restrict__ keep, int n, int words)
{
    __shared__ __align__(16) unsigned char smem[CAPR * 256 + CAPR * 4]; // 61.9KB
    __shared__ int qcnt;

    const int tid = threadIdx.x;
    const int gid = blockIdx.x * 256 + tid;
    cg::grid_group grid = cg::this_grid();

    // ================= phase 0: init (mask/summary zero + box8 prep) ========
    const int rows_total = ((n + 63) >> 6) << 6;
    for (int t = gid; t < rows_total * words; t += NBLOCKS * 256)
        mask[t] = 0ULL;                            // coalesced 8B/lane
    if (gid < 64) summary[gid] = 0ULL;
    if (gid < n) {
        const float* b = boxes + (size_t)gid * 5;
        float x = b[0], y = b[1], w = b[2], h = b[3], th = b[4];
        box8[2 * gid]     = make_float4(x, y, w, h);
        box8[2 * gid + 1] = make_float4(cosf(th), sinf(th),
                                        0.5f * sqrtf(w * w + h * h), w * h);
    }
    grid.sync();

    // ================= phase 1: tiled pair filter ===========================
    {
        unsigned int* q = (unsigned int*)smem;     // 16KB of the overlay

        const int itiles = (n + ITILE - 1) / ITILE;
        const int jtiles = (n + 255) / 256;
        int T = 0;
        for (int q2 = 0; q2 < jtiles; ++q2) {
            int c2 = (q2 * 256 + 254) / ITILE + 1;
            T += (c2 < itiles) ? c2 : itiles;
        }

        for (int L = blockIdx.x; L < T; L += NBLOCKS) {
            // decode L -> (jt, it) over live tiles (uniform, <=8 iters)
            int L2 = L, jt = -1, it = 0;
            for (int q2 = 0; q2 < jtiles; ++q2) {
                int c2 = (q2 * 256 + 254) / ITILE + 1;
                c2 = (c2 < itiles) ? c2 : itiles;
                if (jt < 0) {
                    if (L2 < c2) { jt = q2; it = L2; }
                    else L2 -= c2;
                }
            }
            const int i0 = it * ITILE;
            const int j = jt * 256 + tid;

            if (tid == 0) qcnt = 0;
            __syncthreads();

            float4 B0, B1;
            bool jok = (j < n);
            if (jok) { B0 = box8[2 * j]; B1 = box8[2 * j + 1]; }
            else     { B0 = make_float4(0,0,0,0); B1 = make_float4(0,0,0,0); }

#pragma unroll
            for (int ii = 0; ii < ITILE; ++ii) {
                int i = i0 + ii;
                if (i < n) {                        // uniform branch
                    float4 A0 = box8[2 * i];        // uniform -> s_load
                    float4 A1 = box8[2 * i + 1];
                    bool pass = jok && (j > i);
                    float dx = A0.x - B0.x, dy = A0.y - B0.y;
                    float rr = A1.z + B1.z + 1e-2f;
                    pass = pass && (dx * dx + dy * dy <= rr * rr);
                    float amin = fminf(A1.w, B1.w), amax = fmaxf(A1.w, B1.w);
                    pass = pass && (amin >= 0.699f * amax);
                    if (pass) {
                        int idx = atomicAdd(&qcnt, 1);   // LDS atomic, rare
                        q[idx] = ((unsigned int)i << 16) | (unsigned int)j;
                    }
                }
            }
            __syncthreads();

            int qn = qcnt;                          // <= QCAP by construction
            for (int t = tid; t < qn; t += 256) {
                unsigned int pk = q[t];
                int i2 = (int)(pk >> 16), j2 = (int)(pk & 0xffffu);
                float4 A0 = box8[2 * i2], A1 = box8[2 * i2 + 1];
                float4 C0 = box8[2 * j2], C1 = box8[2 * j2 + 1];
                float a1 = A1.w, a2 = C1.w;
                float inter = rect_inter_area_cs(
                    A0.x, A0.y, A0.z, A0.w, A1.x, A1.y,
                    C0.x, C0.y, C0.z, C0.w, C1.x, C1.y);
                float iou = inter / (a1 + a2 - inter + EPSF);
                if (iou >= NMS_THR) {
                    atomicOr(&mask[(size_t)i2 * words + (j2 >> 6)],
                             1ULL << (j2 & 63));
                    atomicOr(&summary[i2 >> 6], 1ULL << (i2 & 63));
                }
            }
            __syncthreads();                        // q/qcnt reuse next tile
        }
    }
    grid.sync();

    // ================= phase 2: sparse greedy (block 0 only) ================
    if (blockIdx.x != 0) return;
    {
        unsigned long long* rowdat = (unsigned long long*)smem;      // 60KB
        unsigned int* rowlist = (unsigned int*)(smem + CAPR * 256);  // ~1KB
        const int lane = tid & 63;
        if (tid >= 64) return;                      // one wave does greedy
        const int chunks = (n + 63) >> 6;

        unsigned long long szv = (lane < chunks) ? summary[lane] : 0ULL;

        int pc = __popcll(szv);
        int pref = pc;
#pragma unroll
        for (int d = 1; d < 64; d <<= 1) {
            int t = __shfl_up(pref, d);
            if (lane >= d) pref += t;
        }
        int base_excl = pref - pc;
        int R = __shfl(pref, chunks - 1);

        {
            unsigned long long m = szv;
            int s = base_excl;
            while (m && s < CAPR) {
                int k = (int)__builtin_ctzll(m);
                m &= m - 1;
                rowlist[s] = (unsigned int)((lane << 6) + k);
                ++s;
            }
        }
        __builtin_amdgcn_s_barrier();               // wave-level: ds visibility

        int Rc = (R < CAPR) ? R : CAPR;
        if (Rc > 0) {
            int nins = (Rc + 3) >> 2;
            for (int t = 0; t < nins; ++t) {
                int slot = (t << 2) + (lane >> 4);
                int cs = (slot < Rc) ? slot : (Rc - 1);
                unsigned int row = rowlist[cs];
                const char* src = (const char*)(mask + (size_t)row * words)
                                + (size_t)(lane & 15) * 16;
                char* dst = (char*)rowdat + (size_t)t * 1024;
                __builtin_amdgcn_global_load_lds(
                    (const GLOBAL_AS unsigned int*)src,
                    (LDS_AS unsigned int*)dst, 16, 0, 0);
            }
        }
        asm volatile("s_waitcnt vmcnt(0)" ::: "memory");
        __builtin_amdgcn_sched_barrier(0);

        unsigned long long acc = 0ULL;
        int cnt = 0;

        for (int c = 0; c < chunks; ++c) {
            if (cnt >= TOPN) break;
            const int base = c << 6;
            unsigned long long cw = rl64(acc, c);
            unsigned long long nzc = rl64(szv, c);
            unsigned long long valid =
                (n - base >= 64) ? ~0ULL : ((1ULL << (n - base)) - 1ULL);
            unsigned long long cand = ~cw & valid;
            int rem = TOPN - cnt;

            unsigned long long kmask;
            if ((nzc & cand) == 0ULL && __popcll(cand) <= rem) {
                kmask = cand;                       // zero-memory fast path
            } else {
                int bexc = __builtin_amdgcn_readlane(base_excl, c);
                unsigned long long D = 0ULL;
                if ((nzc >> lane) & 1ULL) {
                    int slot = bexc +
                        (int)__popcll(nzc & ((lane == 0) ? 0ULL
                                             : ((~0ULL) >> (64 - lane))));
                    D = (slot < CAPR)
                        ? rowdat[(size_t)slot * 32 + c]
                        : mask[(size_t)(base + lane) * words + c];
                }
                unsigned long long intra = __ballot((D & cand) != 0ULL);
                if ((intra & cand) == 0ULL && __popcll(cand) <= rem) {
                    kmask = cand;                   // parallel decision
                } else {
                    kmask = 0ULL;                   // serial fallback (rare)
                    int cl = cnt;
#pragma unroll
                    for (int k = 0; k < 64; ++k) {
                        if (!((cw >> k) & 1ULL) && cl < TOPN && (base + k) < n) {
                            cw |= rl64(D, k);
                            kmask |= (1ULL << k);
                            ++cl;
                        }
                    }
                }
            }

            if ((kmask >> lane) & 1ULL)
                keep[cnt + __popcll(kmask & ((1ULL << lane) - 1ULL))] =
                    base + lane;
            cnt += __popcll(kmask);

            unsigned long long orrows = kmask & nzc;
            if (orrows) {
                int bexc = __builtin_amdgcn_readlane(base_excl, c);
                while (orrows) {
                    int r = (int)__builtin_ctzll(orrows);
                    orrows &= orrows - 1ULL;
                    int slot = bexc +
                        (int)__popcll(nzc & ((r == 0) ? 0ULL
                                             : ((~0ULL) >> (64 - r))));
                    unsigned long long v = (slot < CAPR)
                        ? rowdat[(size_t)slot * 32 + (lane & 31)]
                        : mask[(size_t)(base + r) * words + (lane & 31)];
                    acc |= v;
                }
            }
        }

        for (int t = cnt + lane; t < TOPN; t += 64) keep[t] = -1;
    }
}

extern "C" void kernel_launch(void* const* d_in, const int* in_sizes, int n_in,
                              void* d_out, int out_size, void* d_ws, size_t ws_size,
                              hipStream_t stream) {
    const float* boxes = (const float*)d_in[0];
    int n = in_sizes[0] / 5;                     // 2048
    int words = (n + 63) / 64;                   // 32
    int rows_total = ((n + 63) / 64) * 64;       // 2048
    int* keep = (int*)d_out;

    // ws layout: mask (rows_total*words*8) | summary (512B) | box8 (n*32B)
    unsigned long long* mask = (unsigned long long*)d_ws;
    size_t mask_alloc = (size_t)rows_total * words * 8;
    unsigned long long* summary =
        (unsigned long long*)((char*)d_ws + mask_alloc);
    float4* box8 = (float4*)((char*)d_ws + mask_alloc + 512);

    void* args[] = {(void*)&boxes, (void*)&box8, (void*)&mask,
                    (void*)&summary, (void*)&keep, (void*)&n, (void*)&words};
    hipLaunchCooperativeKernel((const void*)fused_kernel, dim3(NBLOCKS),
                               dim3(256), args, 0, stream);
}

// Round 10
// 79.492 us; speedup vs baseline: 1.1406x; 1.1406x over previous
//
#include <hip/hip_runtime.h>
#include <hip/hip_bf16.h>

#define CAP 8
#define EPSF 1e-8f
#define NMS_THR 0.7f
#define TOPN 1000
#define ITILE 16                       // i-rows per tile
#define QCAP (256 * ITILE)             // candidate queue: worst-case tile pairs
#define SQCAP 1024                     // suppressing-pair queue per tile
#define CAPR 64                        // LDS row-cache slots (64 * 256B = 16KB)
#define SCRATCH_ROWS 256               // global overflow rows (pathological only)
#define OVF_CAP 8192                   // global overflow pair list

// ---------------------------------------------------------------------------
// agent(device)-scope helpers: cross-XCD visible stores/loads (G16)
// ---------------------------------------------------------------------------
__device__ __forceinline__ void gstore(unsigned int* p, unsigned int v) {
    __hip_atomic_store(p, v, __ATOMIC_RELAXED, __HIP_MEMORY_SCOPE_AGENT);
}
__device__ __forceinline__ unsigned int gload(const unsigned int* p) {
    return __hip_atomic_load(p, __ATOMIC_RELAXED, __HIP_MEMORY_SCOPE_AGENT);
}

// ---------------------------------------------------------------------------
// Rotated-rect intersection area (verified absmax==0 R1-R9): faithful fp32
// Sutherland-Hodgman clip, all compile-time indices, zero scratch.
// ---------------------------------------------------------------------------
__device__ __forceinline__ float rect_inter_area_cs(
    float xc1, float yc1, float w1, float h1, float c1, float s1,
    float xc2, float yc2, float w2, float h2, float c2, float s2)
{
    float px[CAP], py[CAP];
    {
        float lx0 = -0.5f * w1, lx1 = 0.5f * w1;
        float ly0 = -0.5f * h1, ly1 = 0.5f * h1;
        px[0] = xc1 + lx0 * c1 - ly0 * s1;  py[0] = yc1 + lx0 * s1 + ly0 * c1;
        px[1] = xc1 + lx1 * c1 - ly0 * s1;  py[1] = yc1 + lx1 * s1 + ly0 * c1;
        px[2] = xc1 + lx1 * c1 - ly1 * s1;  py[2] = yc1 + lx1 * s1 + ly1 * c1;
        px[3] = xc1 + lx0 * c1 - ly1 * s1;  py[3] = yc1 + lx0 * s1 + ly1 * c1;
#pragma unroll
        for (int s2i = 4; s2i < CAP; ++s2i) { px[s2i] = 0.f; py[s2i] = 0.f; }
    }
    float qx[4], qy[4];
    {
        float lx0 = -0.5f * w2, lx1 = 0.5f * w2;
        float ly0 = -0.5f * h2, ly1 = 0.5f * h2;
        qx[0] = xc2 + lx0 * c2 - ly0 * s2;  qy[0] = yc2 + lx0 * s2 + ly0 * c2;
        qx[1] = xc2 + lx1 * c2 - ly0 * s2;  qy[1] = yc2 + lx1 * s2 + ly0 * c2;
        qx[2] = xc2 + lx1 * c2 - ly1 * s2;  qy[2] = yc2 + lx1 * s2 + ly1 * c2;
        qx[3] = xc2 + lx0 * c2 - ly1 * s2;  qy[3] = yc2 + lx0 * s2 + ly1 * c2;
    }

    int n = 4;
#pragma unroll
    for (int e = 0; e < 4; ++e) {
        float p0x = qx[e], p0y = qy[e];
        float ex = qx[(e + 1) & 3] - p0x, ey = qy[(e + 1) & 3] - p0y;

        float pxp = px[0], pyp = py[0];
#pragma unroll
        for (int s = 1; s < CAP; ++s)
            if (s == n - 1) { pxp = px[s]; pyp = py[s]; }
        float dp = ex * (pyp - p0y) - ey * (pxp - p0x);

        float nx_[CAP], ny_[CAP];
#pragma unroll
        for (int s = 0; s < CAP; ++s) { nx_[s] = 0.f; ny_[s] = 0.f; }
        int m = 0;

#pragma unroll
        for (int k = 0; k < CAP; ++k) {
            bool act = (k < n);
            float pxc = px[k], pyc = py[k];
            float dc = ex * (pyc - p0y) - ey * (pxc - p0x);
            bool cin = (dc >= 0.0f), pin = (dp >= 0.0f);

            float den = dp - dc;
            den = (fabsf(den) < EPSF) ? EPSF : den;
            float t = dp / den;
            float ix = pxp + t * (pxc - pxp);
            float iy = pyp + t * (pyc - pyp);

            bool emit_cross = act && (cin != pin);
            if (emit_cross) {
#pragma unroll
                for (int s = 0; s < CAP; ++s)
                    if (s == m) { nx_[s] = ix; ny_[s] = iy; }
                ++m;
            }
            bool emit_cur = act && cin;
            if (emit_cur) {
#pragma unroll
                for (int s = 0; s < CAP; ++s)
                    if (s == m) { nx_[s] = pxc; ny_[s] = pyc; }
                ++m;
            }
            if (act) { pxp = pxc; pyp = pyc; dp = dc; }
        }
        n = (m < CAP) ? m : CAP;
#pragma unroll
        for (int s = 0; s < CAP; ++s) { px[s] = nx_[s]; py[s] = ny_[s]; }
    }

    if (n < 3) return 0.0f;
    float s = 0.0f;
#pragma unroll
    for (int k = 0; k < CAP; ++k) {
        if (k < n) {
            float nxk = px[(k + 1) & (CAP - 1)];
            float nyk = py[(k + 1) & (CAP - 1)];
            if (k == n - 1) { nxk = px[0]; nyk = py[0]; }
            s += px[k] * nyk - py[k] * nxk;
        }
    }
    return 0.5f * fabsf(s);
}

__device__ __forceinline__ unsigned long long rl64(unsigned long long v, int l) {
    unsigned int lo = (unsigned int)__builtin_amdgcn_readlane((int)(unsigned int)v, l);
    unsigned int hi = (unsigned int)__builtin_amdgcn_readlane((int)(v >> 32), l);
    return ((unsigned long long)hi << 32) | lo;
}

// ---------------------------------------------------------------------------
// ONE kernel, two roles:
//  (a) every block: verified tiled filter (atile in LDS w/ inline trig,
//      candidate q, full-lane clip drain) -> suppressing pairs to a
//      contention-free per-block slice (agent-scope stores, no global counter)
//  (b) LAST block to finish (agent-scope done counter): rebuild sparse rows
//      from the pair list in LDS and run the verified R8 greedy serial core.
// No mask buffer, no init kernel, no kernel-boundary drains.
// ---------------------------------------------------------------------------
__global__ __launch_bounds__(256)
void fused_kernel(const float* __restrict__ boxes,
                  unsigned int* __restrict__ ctrs,       // [0]=done [1]=ovf
                  unsigned int* __restrict__ cnt_per_block,
                  unsigned int* __restrict__ pairs, int slice,
                  unsigned int* __restrict__ ovf_list,
                  unsigned int* __restrict__ scratch32,  // SCRATCH_ROWS*64 u32
                  int* __restrict__ keep, int n, int T)
{
    __shared__ float4 atile[2 * ITILE];
    __shared__ unsigned int q[QCAP];            // 16KB; reused as rowdat in tail
    __shared__ unsigned int sq[SQCAP];          // 4KB
    __shared__ int qcnt, scnt, lastflag;
    __shared__ unsigned int szv32[64];          // 32 chunks x 2 halves
    __shared__ int bexcl_lds[32];
    __shared__ int Rtot;

    const int tid = threadIdx.x;
    const int chunks = (n + 63) >> 6;

    // ---- decode blockIdx -> (jt, it) over live tiles (verified R9) ----
    const int itiles = (n + ITILE - 1) / ITILE;
    const int jtiles = (n + 255) / 256;
    int L2 = blockIdx.x, jt = -1, it = 0;
    for (int q2 = 0; q2 < jtiles; ++q2) {
        int c2 = (q2 * 256 + 254) / ITILE + 1;
        c2 = (c2 < itiles) ? c2 : itiles;
        if (jt < 0) {
            if (L2 < c2) { jt = q2; it = L2; }
            else L2 -= c2;
        }
    }
    const int i0 = it * ITILE;
    const int j = jt * 256 + tid;

    if (tid == 0) { qcnt = 0; scnt = 0; }
    if (tid < ITILE) {                        // inline prep of the i-tile
        int i = i0 + tid;
        if (i < n) {
            const float* b = boxes + (size_t)i * 5;
            float x = b[0], y = b[1], w = b[2], h = b[3], th = b[4];
            atile[2 * tid]     = make_float4(x, y, w, h);
            atile[2 * tid + 1] = make_float4(cosf(th), sinf(th),
                                             0.5f * sqrtf(w * w + h * h), w * h);
        } else {
            atile[2 * tid]     = make_float4(0.f, 0.f, 0.f, 0.f);
            atile[2 * tid + 1] = make_float4(0.f, 0.f, 0.f, 0.f);
        }
    }
    __syncthreads();

    // ---- j-box params in registers (inline prep, same math) ----
    float4 B0, B1;
    bool jok = (j < n);
    if (jok) {
        const float* b = boxes + (size_t)j * 5;
        float x = b[0], y = b[1], w = b[2], h = b[3], th = b[4];
        B0 = make_float4(x, y, w, h);
        B1 = make_float4(cosf(th), sinf(th),
                         0.5f * sqrtf(w * w + h * h), w * h);
    } else { B0 = make_float4(0,0,0,0); B1 = make_float4(0,0,0,0); }

    // ---- cheap-reject sweep (verified R6-R8 math) ----
#pragma unroll
    for (int ii = 0; ii < ITILE; ++ii) {
        int i = i0 + ii;
        float4 A0 = atile[2 * ii], A1 = atile[2 * ii + 1];
        bool pass = jok && (j > i) && (i < n);
        float dx = A0.x - B0.x, dy = A0.y - B0.y;
        float rr = A1.z + B1.z + 1e-2f;
        pass = pass && (dx * dx + dy * dy <= rr * rr);
        float amin = fminf(A1.w, B1.w), amax = fmaxf(A1.w, B1.w);
        pass = pass && (amin >= 0.699f * amax);
        if (pass) {
            int idx = atomicAdd(&qcnt, 1);
            q[idx] = ((unsigned int)ii << 16) | (unsigned int)j;
        }
    }
    __syncthreads();

    // ---- full-lane clip drain; suppressing pairs -> LDS sq ----
    int qn = qcnt;
    for (int t = tid; t < qn; t += 256) {
        unsigned int pk = q[t];
        int ii = (int)(pk >> 16), j2 = (int)(pk & 0xffffu);
        int i2 = i0 + ii;
        float4 A0 = atile[2 * ii], A1 = atile[2 * ii + 1];
        const float* b = boxes + (size_t)j2 * 5;
        float x = b[0], y = b[1], w = b[2], h = b[3], th = b[4];
        float cj = cosf(th), sj = sinf(th);
        float a1 = A1.w, a2 = w * h;
        float inter = rect_inter_area_cs(A0.x, A0.y, A0.z, A0.w, A1.x, A1.y,
                                         x, y, w, h, cj, sj);
        float iou = inter / (a1 + a2 - inter + EPSF);
        if (iou >= NMS_THR) {
            unsigned int pr = ((unsigned int)i2 << 16) | (unsigned int)j2;
            int s2 = atomicAdd(&scnt, 1);
            if (s2 < SQCAP) sq[s2] = pr;
            else {                               // pathological overflow
                unsigned int o = atomicAdd(&ctrs[1], 1u);
                if (o < OVF_CAP) gstore(&ovf_list[o], pr);
            }
        }
    }
    __syncthreads();

    // ---- publish slice (contention-free; agent-scope) ----
    int sn = (scnt < SQCAP) ? scnt : SQCAP;
    int wn = (sn < slice) ? sn : slice;
    for (int t = tid; t < wn; t += 256)
        gstore(&pairs[(size_t)blockIdx.x * slice + t], sq[t]);
    for (int t = slice + tid; t < sn; t += 256) {  // slice overflow -> ovf
        unsigned int o = atomicAdd(&ctrs[1], 1u);
        if (o < OVF_CAP) gstore(&ovf_list[o], sq[t]);
    }
    if (tid == 0) gstore(&cnt_per_block[blockIdx.x], (unsigned int)wn);

    // ---- last-done block runs greedy ----
    __threadfence();
    if (tid == 0) {
        unsigned int old = __hip_atomic_fetch_add(&ctrs[0], 1u,
                                                  __ATOMIC_ACQ_REL,
                                                  __HIP_MEMORY_SCOPE_AGENT);
        lastflag = (old == (unsigned int)(T - 1));
    }
    __syncthreads();
    if (!lastflag) return;
    __threadfence();

    // ================= tail: rebuild rows from pairs, run greedy ============
    unsigned int* rowdat32 = q;                 // overlay: CAPR rows x 64 u32

    for (int t = tid; t < 64; t += 256) szv32[t] = 0u;
    __syncthreads();

    // pass 1: summary bits (LDS atomicOr)
    for (int b = tid; b < T; b += 256) {
        int cb = (int)gload(&cnt_per_block[b]);
        for (int t2 = 0; t2 < cb; ++t2) {
            unsigned int p = gload(&pairs[(size_t)b * slice + t2]);
            int i = (int)(p >> 16);
            atomicOr(&szv32[((i >> 6) << 1) + ((i >> 5) & 1)], 1u << (i & 31));
        }
    }
    int ocnt = (int)gload(&ctrs[1]); if (ocnt > OVF_CAP) ocnt = OVF_CAP;
    for (int t = tid; t < ocnt; t += 256) {
        unsigned int p = gload(&ovf_list[t]);
        int i = (int)(p >> 16);
        atomicOr(&szv32[((i >> 6) << 1) + ((i >> 5) & 1)], 1u << (i & 31));
    }
    __syncthreads();

    // wave0: prefix-scan nonzero-row counts -> slots
    if (tid < 64) {
        int lane = tid;
        unsigned long long szv = (lane < chunks)
            ? ((unsigned long long)szv32[2 * lane] |
               ((unsigned long long)szv32[2 * lane + 1] << 32)) : 0ULL;
        int pc = __popcll(szv);
        int pref = pc;
#pragma unroll
        for (int d = 1; d < 64; d <<= 1) {
            int t = __shfl_up(pref, d);
            if (lane >= d) pref += t;
        }
        if (lane < chunks) bexcl_lds[lane] = pref - pc;
        if (lane == chunks - 1) Rtot = pref;
    }
    __syncthreads();

    int R = Rtot;
    int Rc = (R < CAPR) ? R : CAPR;
    int Rs = ((R < CAPR + SCRATCH_ROWS) ? R : (CAPR + SCRATCH_ROWS)) - Rc;
    for (int t = tid; t < Rc * 64; t += 256) rowdat32[t] = 0u;
    for (int t = tid; t < Rs * 64; t += 256) scratch32[t] = 0u;
    __syncthreads();

    // pass 2: scatter suppression bits into row cache
    for (int b = tid; b < T; b += 256) {
        int cb = (int)gload(&cnt_per_block[b]);
        for (int t2 = 0; t2 < cb; ++t2) {
            unsigned int p = gload(&pairs[(size_t)b * slice + t2]);
            int i = (int)(p >> 16), jj = (int)(p & 0xffffu);
            int c = i >> 6;
            unsigned long long szc =
                (unsigned long long)szv32[2 * c] |
                ((unsigned long long)szv32[2 * c + 1] << 32);
            int slot = bexcl_lds[c] +
                (int)__popcll(szc & (((i & 63) == 0) ? 0ULL
                                     : ((~0ULL) >> (64 - (i & 63)))));
            if (slot < CAPR)
                atomicOr(&rowdat32[slot * 64 + (jj >> 5)], 1u << (jj & 31));
            else if (slot < CAPR + SCRATCH_ROWS)
                atomicOr(&scratch32[(slot - CAPR) * 64 + (jj >> 5)],
                         1u << (jj & 31));
        }
    }
    for (int t = tid; t < ocnt; t += 256) {
        unsigned int p = gload(&ovf_list[t]);
        int i = (int)(p >> 16), jj = (int)(p & 0xffffu);
        int c = i >> 6;
        unsigned long long szc =
            (unsigned long long)szv32[2 * c] |
            ((unsigned long long)szv32[2 * c + 1] << 32);
        int slot = bexcl_lds[c] +
            (int)__popcll(szc & (((i & 63) == 0) ? 0ULL
                                 : ((~0ULL) >> (64 - (i & 63)))));
        if (slot < CAPR)
            atomicOr(&rowdat32[slot * 64 + (jj >> 5)], 1u << (jj & 31));
        else if (slot < CAPR + SCRATCH_ROWS)
            atomicOr(&scratch32[(slot - CAPR) * 64 + (jj >> 5)],
                     1u << (jj & 31));
    }
    __syncthreads();

    // ---- verified R8 serial greedy core (wave 0) ----
    if (tid >= 64) return;
    {
        const int lane = tid;
        unsigned long long szv = (lane < chunks)
            ? ((unsigned long long)szv32[2 * lane] |
               ((unsigned long long)szv32[2 * lane + 1] << 32)) : 0ULL;
        int base_excl = (lane < chunks) ? bexcl_lds[lane] : 0;

        auto rowread = [&](int slot, int word) -> unsigned long long {
            if (slot < CAPR)
                return (unsigned long long)rowdat32[slot * 64 + 2 * word] |
                       ((unsigned long long)rowdat32[slot * 64 + 2 * word + 1]
                        << 32);
            if (slot < CAPR + SCRATCH_ROWS)
                return (unsigned long long)
                           scratch32[(slot - CAPR) * 64 + 2 * word] |
                       ((unsigned long long)
                           scratch32[(slot - CAPR) * 64 + 2 * word + 1] << 32);
            return 0ULL;   // beyond scratch: pathological only
        };

        unsigned long long acc = 0ULL;
        int cnt = 0;

        for (int c = 0; c < chunks; ++c) {
            if (cnt >= TOPN) break;
            const int base = c << 6;
            unsigned long long cw = rl64(acc, c);
            unsigned long long nzc = rl64(szv, c);
            unsigned long long valid =
                (n - base >= 64) ? ~0ULL : ((1ULL << (n - base)) - 1ULL);
            unsigned long long cand = ~cw & valid;
            int rem = TOPN - cnt;

            unsigned long long kmask;
            if ((nzc & cand) == 0ULL && __popcll(cand) <= rem) {
                kmask = cand;                       // zero-memory fast path
            } else {
                int bexc = __builtin_amdgcn_readlane(base_excl, c);
                unsigned long long D = 0ULL;
                if ((nzc >> lane) & 1ULL) {
                    int slot = bexc +
                        (int)__popcll(nzc & ((lane == 0) ? 0ULL
                                             : ((~0ULL) >> (64 - lane))));
                    D = rowread(slot, c);
                }
                unsigned long long intra = __ballot((D & cand) != 0ULL);
                if ((intra & cand) == 0ULL && __popcll(cand) <= rem) {
                    kmask = cand;                   // parallel decision
                } else {
                    kmask = 0ULL;                   // serial fallback (rare)
                    int cl = cnt;
#pragma unroll
                    for (int k = 0; k < 64; ++k) {
                        if (!((cw >> k) & 1ULL) && cl < TOPN && (base + k) < n) {
                            cw |= rl64(D, k);
                            kmask |= (1ULL << k);
                            ++cl;
                        }
                    }
                }
            }

            if ((kmask >> lane) & 1ULL)
                keep[cnt + __popcll(kmask & ((1ULL << lane) - 1ULL))] =
                    base + lane;
            cnt += __popcll(kmask);

            unsigned long long orrows = kmask & nzc;
            if (orrows) {
                int bexc = __builtin_amdgcn_readlane(base_excl, c);
                while (orrows) {
                    int r = (int)__builtin_ctzll(orrows);
                    orrows &= orrows - 1ULL;
                    int slot = bexc +
                        (int)__popcll(nzc & ((r == 0) ? 0ULL
                                             : ((~0ULL) >> (64 - r))));
                    acc |= rowread(slot, lane & 31);
                }
            }
        }

        for (int t = cnt + lane; t < TOPN; t += 64) keep[t] = -1;
    }
}

extern "C" void kernel_launch(void* const* d_in, const int* in_sizes, int n_in,
                              void* d_out, int out_size, void* d_ws, size_t ws_size,
                              hipStream_t stream) {
    const float* boxes = (const float*)d_in[0];
    int n = in_sizes[0] / 5;                     // 2048
    int* keep = (int*)d_out;

    // live-tile count T (same formula as kernel decode)
    const int itiles = (n + ITILE - 1) / ITILE;
    const int jtiles = (n + 255) / 256;
    int T = 0;
    for (int q2 = 0; q2 < jtiles; ++q2) {
        int c2 = (q2 * 256 + 254) / ITILE + 1;
        T += (c2 < itiles) ? c2 : itiles;
    }

    // ws layout: ctrs(16) | cnt_per_block(4T) | pairs(T*slice*4) |
    //            ovf_list(32KB) | scratch(64KB)
    unsigned int* ctrs = (unsigned int*)d_ws;
    unsigned int* cnt_per_block = ctrs + 4;
    size_t off_pairs = ((16 + (size_t)T * 4) + 15) & ~(size_t)15;
    size_t fixed_tail = (size_t)OVF_CAP * 4 + (size_t)SCRATCH_ROWS * 256 + 64;
    long avail = (long)ws_size - (long)off_pairs - (long)fixed_tail;
    int slice = (int)(avail / ((long)T * 4));
    if (slice > 256) slice = 256;
    if (slice < 16) slice = 16;
    unsigned int* pairs = (unsigned int*)((char*)d_ws + off_pairs);
    unsigned int* ovf_list = pairs + (size_t)T * slice;
    unsigned int* scratch32 = ovf_list + OVF_CAP;

    hipMemsetAsync(ctrs, 0, 16, stream);         // done + ovf counters

    fused_kernel<<<T, 256, 0, stream>>>(boxes, ctrs, cnt_per_block, pairs,
                                        slice, ovf_list, scratch32, keep, n, T);
}

// Round 11
// 31.908 us; speedup vs baseline: 2.8415x; 2.4913x over previous
//
#include <hip/hip_runtime.h>
#include <hip/hip_bf16.h>

#define CAP 8
#define EPSF 1e-8f
#define NMS_THR 0.7f
#define TOPN 1000
#define ITILE 16                       // i-rows per tile
#define QCAP (256 * ITILE)             // candidate queue: worst-case tile pairs
#define SQCAP 1024                     // suppressing-pair queue per tile
#define CAPR 64                        // LDS row-cache slots (64 * 256B = 16KB)
#define SCRATCH_ROWS 256               // global overflow rows (pathological only)
#define OVF_CAP 8192                   // global overflow pair list

// ---------------------------------------------------------------------------
// Rotated-rect intersection area (verified absmax==0 R1-R10): faithful fp32
// Sutherland-Hodgman clip, all compile-time indices, zero scratch.
// ---------------------------------------------------------------------------
__device__ __forceinline__ float rect_inter_area_cs(
    float xc1, float yc1, float w1, float h1, float c1, float s1,
    float xc2, float yc2, float w2, float h2, float c2, float s2)
{
    float px[CAP], py[CAP];
    {
        float lx0 = -0.5f * w1, lx1 = 0.5f * w1;
        float ly0 = -0.5f * h1, ly1 = 0.5f * h1;
        px[0] = xc1 + lx0 * c1 - ly0 * s1;  py[0] = yc1 + lx0 * s1 + ly0 * c1;
        px[1] = xc1 + lx1 * c1 - ly0 * s1;  py[1] = yc1 + lx1 * s1 + ly0 * c1;
        px[2] = xc1 + lx1 * c1 - ly1 * s1;  py[2] = yc1 + lx1 * s1 + ly1 * c1;
        px[3] = xc1 + lx0 * c1 - ly1 * s1;  py[3] = yc1 + lx0 * s1 + ly1 * c1;
#pragma unroll
        for (int s2i = 4; s2i < CAP; ++s2i) { px[s2i] = 0.f; py[s2i] = 0.f; }
    }
    float qx[4], qy[4];
    {
        float lx0 = -0.5f * w2, lx1 = 0.5f * w2;
        float ly0 = -0.5f * h2, ly1 = 0.5f * h2;
        qx[0] = xc2 + lx0 * c2 - ly0 * s2;  qy[0] = yc2 + lx0 * s2 + ly0 * c2;
        qx[1] = xc2 + lx1 * c2 - ly0 * s2;  qy[1] = yc2 + lx1 * s2 + ly0 * c2;
        qx[2] = xc2 + lx1 * c2 - ly1 * s2;  qy[2] = yc2 + lx1 * s2 + ly1 * c2;
        qx[3] = xc2 + lx0 * c2 - ly1 * s2;  qy[3] = yc2 + lx0 * s2 + ly1 * c2;
    }

    int n = 4;
#pragma unroll
    for (int e = 0; e < 4; ++e) {
        float p0x = qx[e], p0y = qy[e];
        float ex = qx[(e + 1) & 3] - p0x, ey = qy[(e + 1) & 3] - p0y;

        float pxp = px[0], pyp = py[0];
#pragma unroll
        for (int s = 1; s < CAP; ++s)
            if (s == n - 1) { pxp = px[s]; pyp = py[s]; }
        float dp = ex * (pyp - p0y) - ey * (pxp - p0x);

        float nx_[CAP], ny_[CAP];
#pragma unroll
        for (int s = 0; s < CAP; ++s) { nx_[s] = 0.f; ny_[s] = 0.f; }
        int m = 0;

#pragma unroll
        for (int k = 0; k < CAP; ++k) {
            bool act = (k < n);
            float pxc = px[k], pyc = py[k];
            float dc = ex * (pyc - p0y) - ey * (pxc - p0x);
            bool cin = (dc >= 0.0f), pin = (dp >= 0.0f);

            float den = dp - dc;
            den = (fabsf(den) < EPSF) ? EPSF : den;
            float t = dp / den;
            float ix = pxp + t * (pxc - pxp);
            float iy = pyp + t * (pyc - pyp);

            bool emit_cross = act && (cin != pin);
            if (emit_cross) {
#pragma unroll
                for (int s = 0; s < CAP; ++s)
                    if (s == m) { nx_[s] = ix; ny_[s] = iy; }
                ++m;
            }
            bool emit_cur = act && cin;
            if (emit_cur) {
#pragma unroll
                for (int s = 0; s < CAP; ++s)
                    if (s == m) { nx_[s] = pxc; ny_[s] = pyc; }
                ++m;
            }
            if (act) { pxp = pxc; pyp = pyc; dp = dc; }
        }
        n = (m < CAP) ? m : CAP;
#pragma unroll
        for (int s = 0; s < CAP; ++s) { px[s] = nx_[s]; py[s] = ny_[s]; }
    }

    if (n < 3) return 0.0f;
    float s = 0.0f;
#pragma unroll
    for (int k = 0; k < CAP; ++k) {
        if (k < n) {
            float nxk = px[(k + 1) & (CAP - 1)];
            float nyk = py[(k + 1) & (CAP - 1)];
            if (k == n - 1) { nxk = px[0]; nyk = py[0]; }
            s += px[k] * nyk - py[k] * nxk;
        }
    }
    return 0.5f * fabsf(s);
}

__device__ __forceinline__ unsigned long long rl64(unsigned long long v, int l) {
    unsigned int lo = (unsigned int)__builtin_amdgcn_readlane((int)(unsigned int)v, l);
    unsigned int hi = (unsigned int)__builtin_amdgcn_readlane((int)(v >> 32), l);
    return ((unsigned long long)hi << 32) | lo;
}

// ---------------------------------------------------------------------------
// Kernel 1: tiled pair filter (verified R10 body). Suppressing pairs go to a
// contention-free per-block slice via PLAIN stores — the kernel boundary
// provides cross-XCD visibility (no fences, no done-counter). Rare overflow
// to a global list via one atomic counter.
// ---------------------------------------------------------------------------
__global__ __launch_bounds__(256)
void filter_kernel(const float* __restrict__ boxes,
                   unsigned int* __restrict__ ctrs,       // [1]=ovf counter
                   unsigned int* __restrict__ cnt_per_block,
                   unsigned int* __restrict__ pairs, int slice,
                   unsigned int* __restrict__ ovf_list, int n)
{
    __shared__ float4 atile[2 * ITILE];
    __shared__ unsigned int q[QCAP];            // 16KB candidate queue
    __shared__ unsigned int sq[SQCAP];          // 4KB suppressor queue
    __shared__ int qcnt, scnt;

    const int tid = threadIdx.x;

    // decode blockIdx -> (jt, it) over live tiles (verified R9/R10)
    const int itiles = (n + ITILE - 1) / ITILE;
    const int jtiles = (n + 255) / 256;
    int L2 = blockIdx.x, jt = -1, it = 0;
    for (int q2 = 0; q2 < jtiles; ++q2) {
        int c2 = (q2 * 256 + 254) / ITILE + 1;
        c2 = (c2 < itiles) ? c2 : itiles;
        if (jt < 0) {
            if (L2 < c2) { jt = q2; it = L2; }
            else L2 -= c2;
        }
    }
    const int i0 = it * ITILE;
    const int j = jt * 256 + tid;

    if (tid == 0) { qcnt = 0; scnt = 0; }
    if (tid < ITILE) {                          // inline prep of the i-tile
        int i = i0 + tid;
        if (i < n) {
            const float* b = boxes + (size_t)i * 5;
            float x = b[0], y = b[1], w = b[2], h = b[3], th = b[4];
            atile[2 * tid]     = make_float4(x, y, w, h);
            atile[2 * tid + 1] = make_float4(cosf(th), sinf(th),
                                             0.5f * sqrtf(w * w + h * h), w * h);
        } else {
            atile[2 * tid]     = make_float4(0.f, 0.f, 0.f, 0.f);
            atile[2 * tid + 1] = make_float4(0.f, 0.f, 0.f, 0.f);
        }
    }
    __syncthreads();

    float4 B0, B1;
    bool jok = (j < n);
    if (jok) {
        const float* b = boxes + (size_t)j * 5;
        float x = b[0], y = b[1], w = b[2], h = b[3], th = b[4];
        B0 = make_float4(x, y, w, h);
        B1 = make_float4(cosf(th), sinf(th),
                         0.5f * sqrtf(w * w + h * h), w * h);
    } else { B0 = make_float4(0,0,0,0); B1 = make_float4(0,0,0,0); }

    // cheap-reject sweep (verified R6-R10 math)
#pragma unroll
    for (int ii = 0; ii < ITILE; ++ii) {
        int i = i0 + ii;
        float4 A0 = atile[2 * ii], A1 = atile[2 * ii + 1];
        bool pass = jok && (j > i) && (i < n);
        float dx = A0.x - B0.x, dy = A0.y - B0.y;
        float rr = A1.z + B1.z + 1e-2f;
        pass = pass && (dx * dx + dy * dy <= rr * rr);
        float amin = fminf(A1.w, B1.w), amax = fmaxf(A1.w, B1.w);
        pass = pass && (amin >= 0.699f * amax);
        if (pass) {
            int idx = atomicAdd(&qcnt, 1);
            q[idx] = ((unsigned int)ii << 16) | (unsigned int)j;
        }
    }
    __syncthreads();

    // full-lane clip drain; suppressing pairs -> LDS sq
    int qn = qcnt;
    for (int t = tid; t < qn; t += 256) {
        unsigned int pk = q[t];
        int ii = (int)(pk >> 16), j2 = (int)(pk & 0xffffu);
        int i2 = i0 + ii;
        float4 A0 = atile[2 * ii], A1 = atile[2 * ii + 1];
        const float* b = boxes + (size_t)j2 * 5;
        float x = b[0], y = b[1], w = b[2], h = b[3], th = b[4];
        float cj = cosf(th), sj = sinf(th);
        float a1 = A1.w, a2 = w * h;
        float inter = rect_inter_area_cs(A0.x, A0.y, A0.z, A0.w, A1.x, A1.y,
                                         x, y, w, h, cj, sj);
        float iou = inter / (a1 + a2 - inter + EPSF);
        if (iou >= NMS_THR) {
            unsigned int pr = ((unsigned int)i2 << 16) | (unsigned int)j2;
            int s2 = atomicAdd(&scnt, 1);
            if (s2 < SQCAP) sq[s2] = pr;
            else {
                unsigned int o = atomicAdd(&ctrs[1], 1u);
                if (o < OVF_CAP) ovf_list[o] = pr;
            }
        }
    }
    __syncthreads();

    // publish slice (plain stores; kernel boundary = visibility)
    int sn = (scnt < SQCAP) ? scnt : SQCAP;
    int wn = (sn < slice) ? sn : slice;
    for (int t = tid; t < wn; t += 256)
        pairs[(size_t)blockIdx.x * slice + t] = sq[t];
    for (int t = slice + tid; t < sn; t += 256) {   // slice overflow -> ovf
        unsigned int o = atomicAdd(&ctrs[1], 1u);
        if (o < OVF_CAP) ovf_list[o] = sq[t];
    }
    if (tid == 0) cnt_per_block[blockIdx.x] = (unsigned int)wn;
}

// ---------------------------------------------------------------------------
// Kernel 2: one block, 256 threads. Rebuild sparse suppression rows from the
// pair list into LDS (normal cached loads — no fences/agent-scope), then the
// verified R8/R10 wave-0 greedy serial core.
// ---------------------------------------------------------------------------
__global__ __launch_bounds__(256, 1)
void greedy_kernel(const unsigned int* __restrict__ ctrs,
                   const unsigned int* __restrict__ cnt_per_block,
                   const unsigned int* __restrict__ pairs, int slice,
                   const unsigned int* __restrict__ ovf_list,
                   unsigned int* __restrict__ scratch32,   // SCRATCH_ROWS*64
                   int* __restrict__ keep, int n, int T)
{
    __shared__ unsigned int rowdat32[CAPR * 64];   // 16KB row cache
    __shared__ unsigned int szv32[64];             // 32 chunks x 2 halves
    __shared__ int bexcl_lds[32];
    __shared__ int Rtot;

    const int tid = threadIdx.x;
    const int chunks = (n + 63) >> 6;

    for (int t = tid; t < 64; t += 256) szv32[t] = 0u;
    __syncthreads();

    // pass 1: summary bits
    for (int b = tid; b < T; b += 256) {
        int cb = (int)cnt_per_block[b];
        for (int t2 = 0; t2 < cb; ++t2) {
            unsigned int p = pairs[(size_t)b * slice + t2];
            int i = (int)(p >> 16);
            atomicOr(&szv32[((i >> 6) << 1) + ((i >> 5) & 1)], 1u << (i & 31));
        }
    }
    int ocnt = (int)ctrs[1]; if (ocnt > OVF_CAP) ocnt = OVF_CAP;
    for (int t = tid; t < ocnt; t += 256) {
        unsigned int p = ovf_list[t];
        int i = (int)(p >> 16);
        atomicOr(&szv32[((i >> 6) << 1) + ((i >> 5) & 1)], 1u << (i & 31));
    }
    __syncthreads();

    // wave0: prefix-scan nonzero-row counts -> slot bases
    if (tid < 64) {
        int lane = tid;
        unsigned long long szv = (lane < chunks)
            ? ((unsigned long long)szv32[2 * lane] |
               ((unsigned long long)szv32[2 * lane + 1] << 32)) : 0ULL;
        int pc = __popcll(szv);
        int pref = pc;
#pragma unroll
        for (int d = 1; d < 64; d <<= 1) {
            int t = __shfl_up(pref, d);
            if (lane >= d) pref += t;
        }
        if (lane < chunks) bexcl_lds[lane] = pref - pc;
        if (lane == chunks - 1) Rtot = pref;
    }
    __syncthreads();

    int R = Rtot;
    int Rc = (R < CAPR) ? R : CAPR;
    int Rs = ((R < CAPR + SCRATCH_ROWS) ? R : (CAPR + SCRATCH_ROWS)) - Rc;
    for (int t = tid; t < Rc * 64; t += 256) rowdat32[t] = 0u;
    for (int t = tid; t < Rs * 64; t += 256) scratch32[t] = 0u;
    __syncthreads();

    // pass 2: scatter suppression bits into the row cache
    for (int b = tid; b < T; b += 256) {
        int cb = (int)cnt_per_block[b];
        for (int t2 = 0; t2 < cb; ++t2) {
            unsigned int p = pairs[(size_t)b * slice + t2];
            int i = (int)(p >> 16), jj = (int)(p & 0xffffu);
            int c = i >> 6;
            unsigned long long szc =
                (unsigned long long)szv32[2 * c] |
                ((unsigned long long)szv32[2 * c + 1] << 32);
            int slot = bexcl_lds[c] +
                (int)__popcll(szc & (((i & 63) == 0) ? 0ULL
                                     : ((~0ULL) >> (64 - (i & 63)))));
            if (slot < CAPR)
                atomicOr(&rowdat32[slot * 64 + (jj >> 5)], 1u << (jj & 31));
            else if (slot < CAPR + SCRATCH_ROWS)
                atomicOr(&scratch32[(slot - CAPR) * 64 + (jj >> 5)],
                         1u << (jj & 31));
        }
    }
    for (int t = tid; t < ocnt; t += 256) {
        unsigned int p = ovf_list[t];
        int i = (int)(p >> 16), jj = (int)(p & 0xffffu);
        int c = i >> 6;
        unsigned long long szc =
            (unsigned long long)szv32[2 * c] |
            ((unsigned long long)szv32[2 * c + 1] << 32);
        int slot = bexcl_lds[c] +
            (int)__popcll(szc & (((i & 63) == 0) ? 0ULL
                                 : ((~0ULL) >> (64 - (i & 63)))));
        if (slot < CAPR)
            atomicOr(&rowdat32[slot * 64 + (jj >> 5)], 1u << (jj & 31));
        else if (slot < CAPR + SCRATCH_ROWS)
            atomicOr(&scratch32[(slot - CAPR) * 64 + (jj >> 5)],
                     1u << (jj & 31));
    }
    __syncthreads();

    // verified R8/R10 serial greedy core (wave 0)
    if (tid >= 64) return;
    {
        const int lane = tid;
        unsigned long long szv = (lane < chunks)
            ? ((unsigned long long)szv32[2 * lane] |
               ((unsigned long long)szv32[2 * lane + 1] << 32)) : 0ULL;
        int base_excl = (lane < chunks) ? bexcl_lds[lane] : 0;

        auto rowread = [&](int slot, int word) -> unsigned long long {
            if (slot < CAPR)
                return (unsigned long long)rowdat32[slot * 64 + 2 * word] |
                       ((unsigned long long)rowdat32[slot * 64 + 2 * word + 1]
                        << 32);
            if (slot < CAPR + SCRATCH_ROWS)
                return (unsigned long long)
                           scratch32[(slot - CAPR) * 64 + 2 * word] |
                       ((unsigned long long)
                           scratch32[(slot - CAPR) * 64 + 2 * word + 1] << 32);
            return 0ULL;   // beyond scratch: pathological only
        };

        unsigned long long acc = 0ULL;
        int cnt = 0;

        for (int c = 0; c < chunks; ++c) {
            if (cnt >= TOPN) break;
            const int base = c << 6;
            unsigned long long cw = rl64(acc, c);
            unsigned long long nzc = rl64(szv, c);
            unsigned long long valid =
                (n - base >= 64) ? ~0ULL : ((1ULL << (n - base)) - 1ULL);
            unsigned long long cand = ~cw & valid;
            int rem = TOPN - cnt;

            unsigned long long kmask;
            if ((nzc & cand) == 0ULL && __popcll(cand) <= rem) {
                kmask = cand;                       // zero-memory fast path
            } else {
                int bexc = __builtin_amdgcn_readlane(base_excl, c);
                unsigned long long D = 0ULL;
                if ((nzc >> lane) & 1ULL) {
                    int slot = bexc +
                        (int)__popcll(nzc & ((lane == 0) ? 0ULL
                                             : ((~0ULL) >> (64 - lane))));
                    D = rowread(slot, c);
                }
                unsigned long long intra = __ballot((D & cand) != 0ULL);
                if ((intra & cand) == 0ULL && __popcll(cand) <= rem) {
                    kmask = cand;                   // parallel decision
                } else {
                    kmask = 0ULL;                   // serial fallback (rare)
                    int cl = cnt;
#pragma unroll
                    for (int k = 0; k < 64; ++k) {
                        if (!((cw >> k) & 1ULL) && cl < TOPN && (base + k) < n) {
                            cw |= rl64(D, k);
                            kmask |= (1ULL << k);
                            ++cl;
                        }
                    }
                }
            }

            if ((kmask >> lane) & 1ULL)
                keep[cnt + __popcll(kmask & ((1ULL << lane) - 1ULL))] =
                    base + lane;
            cnt += __popcll(kmask);

            unsigned long long orrows = kmask & nzc;
            if (orrows) {
                int bexc = __builtin_amdgcn_readlane(base_excl, c);
                while (orrows) {
                    int r = (int)__builtin_ctzll(orrows);
                    orrows &= orrows - 1ULL;
                    int slot = bexc +
                        (int)__popcll(nzc & ((r == 0) ? 0ULL
                                             : ((~0ULL) >> (64 - r))));
                    acc |= rowread(slot, lane & 31);
                }
            }
        }

        for (int t = cnt + lane; t < TOPN; t += 64) keep[t] = -1;
    }
}

extern "C" void kernel_launch(void* const* d_in, const int* in_sizes, int n_in,
                              void* d_out, int out_size, void* d_ws, size_t ws_size,
                              hipStream_t stream) {
    const float* boxes = (const float*)d_in[0];
    int n = in_sizes[0] / 5;                     // 2048
    int* keep = (int*)d_out;

    // live-tile count T (same formula as kernel decode)
    const int itiles = (n + ITILE - 1) / ITILE;
    const int jtiles = (n + 255) / 256;
    int T = 0;
    for (int q2 = 0; q2 < jtiles; ++q2) {
        int c2 = (q2 * 256 + 254) / ITILE + 1;
        T += (c2 < itiles) ? c2 : itiles;
    }

    // ws layout: ctrs(16) | cnt_per_block(4T) | pairs(T*slice*4) |
    //            ovf_list(32KB) | scratch(64KB)
    unsigned int* ctrs = (unsigned int*)d_ws;
    unsigned int* cnt_per_block = ctrs + 4;
    size_t off_pairs = ((16 + (size_t)T * 4) + 15) & ~(size_t)15;
    size_t fixed_tail = (size_t)OVF_CAP * 4 + (size_t)SCRATCH_ROWS * 256 + 64;
    long avail = (long)ws_size - (long)off_pairs - (long)fixed_tail;
    int slice = (int)(avail / ((long)T * 4));
    if (slice > 256) slice = 256;
    if (slice < 16) slice = 16;
    unsigned int* pairs = (unsigned int*)((char*)d_ws + off_pairs);
    unsigned int* ovf_list = pairs + (size_t)T * slice;
    unsigned int* scratch32 = ovf_list + OVF_CAP;

    hipMemsetAsync(ctrs, 0, 16, stream);         // ovf counter

    filter_kernel<<<T, 256, 0, stream>>>(boxes, ctrs, cnt_per_block, pairs,
                                         slice, ovf_list, n);
    greedy_kernel<<<1, 256, 0, stream>>>(ctrs, cnt_per_block, pairs, slice,
                                         ovf_list, scratch32, keep, n, T);
}